// Round 1
// 134.083 us; speedup vs baseline: 1.0179x; 1.0179x over previous
//
#include <hip/hip_runtime.h>
#include <hip/hip_bf16.h>
#include <math.h>

#define Bn 8
#define Tn 1024
#define Vn 2048

typedef __attribute__((ext_vector_type(8))) __bf16 bf16x8;
typedef __attribute__((ext_vector_type(4))) float floatx4;

#define GLDS(gp, lp) \
    __builtin_amdgcn_global_load_lds( \
        (const __attribute__((address_space(1))) void*)(gp), \
        (__attribute__((address_space(3))) void*)(lp), 16, 0, 0)

// ---------------- K0: fused prep.
// blockIdx.y < Bn : gather  Abf[b][t][k] = bf16(W[idx[b,t], idx[b,k]]), k < kmax(t)
// blockIdx.y == Bn: BT[s][k] = (k<=s) ? bf16(exp(vw[s-k])/C[s]) : 0,  C[s]=sum_{d<=s}exp(vw[d])
__global__ __launch_bounds__(256) void k_prep(const int* __restrict__ idx,
                                              const float* __restrict__ W,
                                              const float* __restrict__ vw,
                                              __hip_bfloat16* __restrict__ Abf,
                                              __hip_bfloat16* __restrict__ BT) {
    __shared__ __align__(16) float sbuf[Vn];  // gather: staged W row; bt: reduction scratch
    int tid = threadIdx.x;
    if (blockIdx.y == Bn) {
        int s = blockIdx.x;
        int wave = tid >> 6, lane = tid & 63;
        float part = 0.0f;
#pragma unroll
        for (int i = 0; i < 4; ++i) {
            int d = tid + i * 256;
            if (d <= s) part += __expf(vw[d]);
        }
#pragma unroll
        for (int off = 32; off > 0; off >>= 1) part += __shfl_xor(part, off);
        if (lane == 0) sbuf[wave] = part;
        __syncthreads();
        float cinv = 1.0f / (sbuf[0] + sbuf[1] + sbuf[2] + sbuf[3]);
        int k0 = tid * 4;
        ushort u[4];
#pragma unroll
        for (int j = 0; j < 4; ++j) {
            int k = k0 + j;
            float v = (k <= s) ? __expf(vw[s - k]) * cinv : 0.0f;
            __hip_bfloat16 h = __float2bfloat16(v);
            u[j] = *reinterpret_cast<ushort*>(&h);
        }
        *reinterpret_cast<ushort4*>(&BT[(size_t)s * Tn + k0]) =
            make_ushort4(u[0], u[1], u[2], u[3]);
    } else {
        int b = blockIdx.y, t = blockIdx.x;
        int wave = tid >> 6;
        int r = idx[b * Tn + t];  // block-uniform (scalar load)
        const float* Wr = W + (size_t)r * Vn;
        // global_load_lds staging: per-lane global addr, wave-uniform LDS base + lane*16
#pragma unroll
        for (int i = 0; i < 2; ++i) {
            GLDS(Wr + i * 1024 + tid * 4, &sbuf[i * 1024 + wave * 256]);
        }
        int kmax = ((t >> 7) + 1) << 7;  // GEMM never reads k >= kmax(t)
        int k0 = tid * 4;
        int4 c4 = make_int4(0, 0, 0, 0);
        if (k0 < kmax) c4 = *reinterpret_cast<const int4*>(&idx[b * Tn + k0]);
        __syncthreads();  // compiler drains vmcnt(0) here -> GLDS data landed
        if (k0 < kmax) {
            ushort u[4];
            __hip_bfloat16 h;
            h = __float2bfloat16(sbuf[c4.x]); u[0] = *reinterpret_cast<ushort*>(&h);
            h = __float2bfloat16(sbuf[c4.y]); u[1] = *reinterpret_cast<ushort*>(&h);
            h = __float2bfloat16(sbuf[c4.z]); u[2] = *reinterpret_cast<ushort*>(&h);
            h = __float2bfloat16(sbuf[c4.w]); u[3] = *reinterpret_cast<ushort*>(&h);
            *reinterpret_cast<ushort4*>(&Abf[((size_t)(b * Tn + t)) * Tn + k0]) =
                make_ushort4(u[0], u[1], u[2], u[3]);
        }
    }
}

// ---------------- K1: per-b lower-triangle GEMM, K-trim + 2-way split-K,
// 2-phase pipelined global_load_lds staging (double-buffered LDS, counted vmcnt,
// raw s_barrier so prefetch loads stay in flight across barriers), BK=64 ----------------
#define TM 128
#define TN 128
#define NCHUNK 46
#define BUFE (16 * 512)  // elements per LDS buffer (A or B), 16 KB

// chunk tables, K ranges in BK=64 units, heavy-first
__device__ const signed char CH_MI[NCHUNK] = {7,7,6,7,5,6,7,4,5,6,7,3,4,5,6,7,
                                              6,7,2,3,4,5,6,7,
                                              5,6,7,1,2,3,4,5,6,7,
                                              4,5,6,7,0,1,2,3,4,5,6,7};
__device__ const signed char CH_NI[NCHUNK] = {7,7,6,6,5,5,5,4,4,4,4,3,3,3,3,3,
                                              6,6,2,2,2,2,2,2,
                                              5,5,5,1,1,1,1,1,1,1,
                                              4,4,4,4,0,0,0,0,0,0,0,0};
__device__ const signed char CH_K0[NCHUNK] = {0,8,0,0,0,0,0,0,0,0,0,0,0,0,0,0,
                                              8,8,0,0,0,0,0,0,
                                              8,8,8,0,0,0,0,0,0,0,
                                              8,8,8,8,0,0,0,0,0,0,0,0};
__device__ const signed char CH_K1[NCHUNK] = {8,16,8,8,8,8,8,8,8,8,8,8,8,8,8,8,
                                              14,14,6,6,6,6,6,6,
                                              12,12,12,4,4,4,4,4,4,4,
                                              10,10,10,10,2,2,2,2,2,2,2,2};
__device__ const signed char CH_P[NCHUNK]  = {0,1,0,0,0,0,0,0,0,0,0,0,0,0,0,0,
                                              1,1,0,0,0,0,0,0,
                                              1,1,1,0,0,0,0,0,0,0,
                                              1,1,1,1,0,0,0,0,0,0,0,0};

__global__ __launch_bounds__(256) void k_gemm(const __hip_bfloat16* __restrict__ A,
                                              const __hip_bfloat16* __restrict__ BT,
                                              float* __restrict__ part0,
                                              float* __restrict__ part1) {
    // fragment-ordered LDS: chunk c (= h*8 + sub) holds 64 lanes x 16B;
    // lane l of chunk c = X[sub*16 + (l&15)][h*32 + (l>>4)*8 .. +8)
    __shared__ __align__(16) __hip_bfloat16 As[2 * BUFE];  // 32 KB, double-buffered
    __shared__ __align__(16) __hip_bfloat16 Bs[2 * BUFE];  // 32 KB
    int b = blockIdx.x;  // batch fastest -> heavy chunks dispatched first
    int cidx = blockIdx.y;
    int mi = CH_MI[cidx], ni = CH_NI[cidx];
    int ki0 = CH_K0[cidx], ki1 = CH_K1[cidx];
    int m0 = mi * TM, n0 = ni * TN;
    int tid = threadIdx.x;
    int wave = tid >> 6, lane = tid & 63;
    int lr = lane & 15, lq = lane >> 4;
    int wmsub = (wave >> 1) * 4, wnsub = (wave & 1) * 4;  // fragment sub-tile bases

    const __hip_bfloat16* Ab = A + (size_t)b * Tn * Tn;

    // per-wave staging assignment: chunks 4*wave .. 4*wave+3 for both A and B
    const __hip_bfloat16* aS[4];
    const __hip_bfloat16* bS[4];
    __hip_bfloat16* aD[4];
    __hip_bfloat16* bD[4];
#pragma unroll
    for (int j = 0; j < 4; ++j) {
        int c = wave * 4 + j;
        int sub = c & 7, h = c >> 3;
        aS[j] = Ab + (size_t)(m0 + sub * 16 + lr) * Tn + h * 32 + lq * 8;
        bS[j] = BT + (size_t)(n0 + sub * 16 + lr) * Tn + h * 32 + lq * 8;
        aD[j] = &As[c * 512];
        bD[j] = &Bs[c * 512];
    }

    floatx4 acc[4][4];
#pragma unroll
    for (int i = 0; i < 4; ++i)
#pragma unroll
        for (int j = 0; j < 4; ++j) acc[i][j] = (floatx4){0.f, 0.f, 0.f, 0.f};

    // prologue: stage first K-block into buffer 0 (8 GLDS per wave)
#pragma unroll
    for (int j = 0; j < 4; ++j) {
        GLDS(aS[j] + ki0 * 64, aD[j]);
        GLDS(bS[j] + ki0 * 64, bD[j]);
    }

    for (int ki = ki0; ki < ki1; ++ki) {
        int p = (ki - ki0) & 1;
        if (ki + 1 < ki1) {
            // issue next K-block into the other buffer; its 8 loads stay in flight
            int ko = (ki + 1) * 64;
            int off = (p ^ 1) * BUFE;
#pragma unroll
            for (int j = 0; j < 4; ++j) {
                GLDS(aS[j] + ko, aD[j] + off);
                GLDS(bS[j] + ko, bD[j] + off);
            }
            // wait only for the oldest 8 (current buffer); 8 prefetch loads remain outstanding
            asm volatile("s_waitcnt vmcnt(8)" ::: "memory");
        } else {
            asm volatile("s_waitcnt vmcnt(0)" ::: "memory");
        }
        __builtin_amdgcn_s_barrier();           // all waves' current-buffer data in LDS
        __builtin_amdgcn_sched_barrier(0);      // no ds_read hoisting above the barrier

        const __hip_bfloat16* Asp = As + p * BUFE;
        const __hip_bfloat16* Bsp = Bs + p * BUFE;
        bf16x8 af[2][4], bfr[2][4];
#pragma unroll
        for (int h = 0; h < 2; ++h) {
#pragma unroll
            for (int m = 0; m < 4; ++m)
                af[h][m] = *reinterpret_cast<const bf16x8*>(
                    &Asp[(h * 8 + wmsub + m) * 512 + lane * 8]);
#pragma unroll
            for (int n = 0; n < 4; ++n)
                bfr[h][n] = *reinterpret_cast<const bf16x8*>(
                    &Bsp[(h * 8 + wnsub + n) * 512 + lane * 8]);
        }
#pragma unroll
        for (int h = 0; h < 2; ++h)
#pragma unroll
            for (int m = 0; m < 4; ++m)
#pragma unroll
                for (int n = 0; n < 4; ++n)
                    acc[m][n] = __builtin_amdgcn_mfma_f32_16x16x32_bf16(
                        af[h][m], bfr[h][n], acc[m][n], 0, 0, 0);

        __builtin_amdgcn_sched_barrier(0);      // keep reads/MFMAs before the close barrier
        __builtin_amdgcn_s_barrier();           // all waves done reading buffer p
    }

    float* Cb = (CH_P[cidx] ? part1 : part0) + (size_t)b * Tn * Tn;
    int quad = lane >> 4;
#pragma unroll
    for (int m = 0; m < 4; ++m)
#pragma unroll
        for (int n = 0; n < 4; ++n)
#pragma unroll
            for (int r = 0; r < 4; ++r) {
                int row = m0 + wmsub * 16 + m * 16 + quad * 4 + r;  // C/D: row = quad*4+reg
                int col = n0 + wnsub * 16 + n * 16 + lr;            //      col = lane&15
                Cb[(size_t)row * Tn + col] = acc[m][n][r];
            }
}

// ---------------- K2: softmax (no max shift; |a2|<0.2) over s<=t, scatter into logits ----------------
__global__ __launch_bounds__(256) void k_softscat(const float* __restrict__ part0,
                                                  const float* __restrict__ part1,
                                                  const int* __restrict__ idx,
                                                  float* __restrict__ out) {
    __shared__ float sh[Vn];
    __shared__ float red[4];
    int t = blockIdx.x, b = blockIdx.y, tid = threadIdx.x;
    int wave = tid >> 6, lane = tid & 63;
#pragma unroll
    for (int i = 0; i < Vn / 256; ++i) sh[tid + i * 256] = 0.0f;

    size_t rowoff = ((size_t)b * Tn + t) * Tn;
    int s0 = tid * 4;
    float v[4] = {0.f, 0.f, 0.f, 0.f};
    if (s0 <= t) {
        float4 v4 = *reinterpret_cast<const float4*>(&part0[rowoff + s0]);
        v[0] = v4.x; v[1] = v4.y; v[2] = v4.z; v[3] = v4.w;
        if (s0 >= 512) {  // split-K second partial exists exactly for s>=512
            float4 w4 = *reinterpret_cast<const float4*>(&part1[rowoff + s0]);
            v[0] += w4.x; v[1] += w4.y; v[2] += w4.z; v[3] += w4.w;
        }
    }
    int4 c4 = *reinterpret_cast<const int4*>(&idx[b * Tn + s0]);
    float e[4];
    float lsum = 0.f;
#pragma unroll
    for (int j = 0; j < 4; ++j) {
        e[j] = (s0 + j <= t) ? __expf(v[j]) : 0.0f;
        lsum += e[j];
    }
#pragma unroll
    for (int off = 32; off > 0; off >>= 1) lsum += __shfl_xor(lsum, off);
    if (lane == 0) red[wave] = lsum;
    __syncthreads();  // also covers sh zeroing
    float inv = 1.0f / (red[0] + red[1] + red[2] + red[3]);
    int c[4] = {c4.x, c4.y, c4.z, c4.w};
#pragma unroll
    for (int j = 0; j < 4; ++j)
        if (s0 + j <= t) atomicAdd(&sh[c[j]], e[j] * inv);
    __syncthreads();
    float* orow = out + ((size_t)b * Tn + t) * Vn;
#pragma unroll
    for (int i = 0; i < Vn / (256 * 4); ++i) {
        floatx4 val = *reinterpret_cast<const floatx4*>(&sh[(tid + i * 256) * 4]);
        __builtin_nontemporal_store(val,
            reinterpret_cast<floatx4*>(&orow[(tid + i * 256) * 4]));
    }
}

extern "C" void kernel_launch(void* const* d_in, const int* in_sizes, int n_in,
                              void* d_out, int out_size, void* d_ws, size_t ws_size,
                              hipStream_t stream) {
    const int* idx = (const int*)d_in[0];
    const float* vw = (const float*)d_in[1];
    const float* W = (const float*)d_in[2];
    float* out = (float*)d_out;
    char* ws = (char*)d_ws;

    __hip_bfloat16* BT = (__hip_bfloat16*)(ws);                 // 2 MB
    __hip_bfloat16* Abf = (__hip_bfloat16*)(ws + (2u << 20));   // 16 MB
    float* part0 = (float*)(ws + (18u << 20));                  // 33.6 MB
    float* part1 = (float*)(ws + (52u << 20));                  // 33.6 MB

    k_prep<<<dim3(Tn, Bn + 1), 256, 0, stream>>>(idx, W, vw, Abf, BT);
    k_gemm<<<dim3(Bn, NCHUNK), 256, 0, stream>>>(Abf, BT, part0, part1);
    k_softscat<<<dim3(Tn, Bn), 256, 0, stream>>>(part0, part1, idx, out);
}